// Round 12
// baseline (143.640 us; speedup 1.0000x reference)
//
#include <hip/hip_runtime.h>
#include <hip/hip_bf16.h>

#define N_NODES 40000
#define N_EDGES 640000

typedef __attribute__((ext_vector_type(8))) short bfrag;   // 8 bf16
typedef __attribute__((ext_vector_type(4))) float ffrag;   // 4 fp32 acc

__device__ __forceinline__ float b2f_lo(unsigned u) {
    return __builtin_bit_cast(float, u << 16);
}
__device__ __forceinline__ float b2f_hi(unsigned u) {
    return __builtin_bit_cast(float, u & 0xffff0000u);
}
__device__ __forceinline__ unsigned short f2b(float f) {
    return __builtin_bit_cast(unsigned short, __float2bfloat16(f));
}

// ---------------- prep: rowptr (int4 adjacent-diff) + Wt123 (k-parallel) ----
#define RP_BLOCKS 782     // ceil((640000/4 + 40001)/256)
#define W_BLOCKS  32
__global__ __launch_bounds__(256) void prep(const int* __restrict__ dst,
                                            int* __restrict__ rowptr,
                                            const float* __restrict__ W1,
                                            const float* __restrict__ W2,
                                            const float* __restrict__ W3,
                                            unsigned short* __restrict__ Wt123) {
    __shared__ float uS[4][128];
    const int bid = blockIdx.x;
    if (bid < RP_BLOCKS) {
        int i = bid * 256 + threadIdx.x;
        if (i < N_EDGES / 4) {
            int e = i * 4;
            int4 d4 = *(const int4*)(dst + e);
            int dp = (e == 0) ? -1 : dst[e - 1];
            for (int n = dp + 1;   n <= d4.x; n++) rowptr[n] = e;
            for (int n = d4.x + 1; n <= d4.y; n++) rowptr[n] = e + 1;
            for (int n = d4.y + 1; n <= d4.z; n++) rowptr[n] = e + 2;
            for (int n = d4.z + 1; n <= d4.w; n++) rowptr[n] = e + 3;
        } else if (i < N_EDGES / 4 + N_NODES + 1) {
            int n = i - N_EDGES / 4;           // 0..N_NODES
            if (n > dst[N_EDGES - 1]) rowptr[n] = N_EDGES;
        }
        return;
    }

    // weight chain: one wave per k (128 waves) — latency hidden by TLP
    const int wv   = threadIdx.x >> 6;
    const int lane = threadIdx.x & 63;
    const int k    = (bid - RP_BLOCKS) * 4 + wv;   // 0..127

    float u0 = 0.f, u1 = 0.f;
    const float* w1p = W1 + k * 128;
    const float* w2p = W2 + 2 * lane;
#pragma unroll 8
    for (int j = 0; j < 128; j++) {
        float a  = w1p[j];
        float2 w = *(const float2*)(w2p + (size_t)j * 128);
        u0 += a * w.x;
        u1 += a * w.y;
    }
    uS[wv][2 * lane]     = u0;
    uS[wv][2 * lane + 1] = u1;
    __syncthreads();

    float acc = 0.f;
    const float* w3p = W3 + lane;
#pragma unroll 8
    for (int l = 0; l < 128; l++)
        acc += uS[wv][l] * w3p[(size_t)l * 64];
    Wt123[lane * 128 + k] = f2b(acc);
}

// ---------------- MFMA GEMM: T[N,64] = bf16( X[N,128] @ W123 ) ----------------
__global__ __launch_bounds__(256) void gemm_mfma64(const float* __restrict__ X,
                                                   const unsigned short* __restrict__ Wt,
                                                   unsigned short* __restrict__ Y) {
    const int wv   = threadIdx.x >> 6;
    const int lane = threadIdx.x & 63;
    const int ml   = lane & 15;
    const int quad = lane >> 4;
    const int row0 = blockIdx.x * 64 + wv * 16;

    ffrag acc[4];
#pragma unroll
    for (int c = 0; c < 4; c++) acc[c] = (ffrag)0.f;

#pragma unroll
    for (int kb = 0; kb < 128; kb += 32) {
        const float* p = X + (size_t)(row0 + ml) * 128 + kb + quad * 8;
        float4 u0 = *(const float4*)p;
        float4 u1 = *(const float4*)(p + 4);
        bfrag a;
        a[0] = (short)f2b(u0.x); a[1] = (short)f2b(u0.y);
        a[2] = (short)f2b(u0.z); a[3] = (short)f2b(u0.w);
        a[4] = (short)f2b(u1.x); a[5] = (short)f2b(u1.y);
        a[6] = (short)f2b(u1.z); a[7] = (short)f2b(u1.w);
#pragma unroll
        for (int c = 0; c < 4; c++) {
            const int col = c * 16 + ml;
            bfrag b = *(const bfrag*)(Wt + (size_t)col * 128 + kb + quad * 8);
            acc[c] = __builtin_amdgcn_mfma_f32_16x16x32_bf16(a, b, acc[c], 0, 0, 0);
        }
    }
#pragma unroll
    for (int c = 0; c < 4; c++)
#pragma unroll
        for (int i = 0; i < 4; i++)
            Y[(size_t)(row0 + quad * 4 + i) * 64 + c * 16 + ml] = f2b(acc[c][i]);
}

// ---------------- CSR scatter, D=64, bf16 in, split-node ----------------
// 4 nodes per wave; TWO 8-lane groups per node take alternate 4-edge chunks
// (halves dependent latency rounds, 10000 waves -> full occupancy); lane owns
// 8 cols via one 16B uint4 load; halves combined with shfl_xor(8).
template<bool OUT_F32>
__global__ __launch_bounds__(256) void scatter8(const unsigned short* __restrict__ T,
                                                const int* __restrict__ srcE,
                                                const int* __restrict__ rowptr,
                                                void* __restrict__ Hv) {
    const int wave = blockIdx.x * 4 + (threadIdx.x >> 6);
    const int lane = threadIdx.x & 63;
    const int grp  = lane >> 3;          // 0..7
    const int sub  = grp & 1;            // half-node id
    const int node = wave * 4 + (grp >> 1);
    const int c8   = (lane & 7) * 8;     // cols c8..c8+7
    if (node >= N_NODES) return;
    const int e0 = rowptr[node], e1 = rowptr[node + 1];

    float a0 = 0.f, a1 = 0.f, a2 = 0.f, a3 = 0.f;
    float a4 = 0.f, a5 = 0.f, a6 = 0.f, a7 = 0.f;

    const int nfull = (e1 - e0) >> 3;
    for (int i = 0; i < nfull; i++) {
        const int base = e0 + i * 8 + sub * 4;
        int s0 = srcE[base], s1 = srcE[base + 1], s2 = srcE[base + 2], s3 = srcE[base + 3];
        uint4 t0 = *(const uint4*)(T + (size_t)s0 * 64 + c8);
        uint4 t1 = *(const uint4*)(T + (size_t)s1 * 64 + c8);
        uint4 t2 = *(const uint4*)(T + (size_t)s2 * 64 + c8);
        uint4 t3 = *(const uint4*)(T + (size_t)s3 * 64 + c8);
        a0 += (b2f_lo(t0.x) + b2f_lo(t1.x)) + (b2f_lo(t2.x) + b2f_lo(t3.x));
        a1 += (b2f_hi(t0.x) + b2f_hi(t1.x)) + (b2f_hi(t2.x) + b2f_hi(t3.x));
        a2 += (b2f_lo(t0.y) + b2f_lo(t1.y)) + (b2f_lo(t2.y) + b2f_lo(t3.y));
        a3 += (b2f_hi(t0.y) + b2f_hi(t1.y)) + (b2f_hi(t2.y) + b2f_hi(t3.y));
        a4 += (b2f_lo(t0.z) + b2f_lo(t1.z)) + (b2f_lo(t2.z) + b2f_lo(t3.z));
        a5 += (b2f_hi(t0.z) + b2f_hi(t1.z)) + (b2f_hi(t2.z) + b2f_hi(t3.z));
        a6 += (b2f_lo(t0.w) + b2f_lo(t1.w)) + (b2f_lo(t2.w) + b2f_lo(t3.w));
        a7 += (b2f_hi(t0.w) + b2f_hi(t1.w)) + (b2f_hi(t2.w) + b2f_hi(t3.w));
    }
    // tail: r = 0..7 edges; sub0 takes first min(r,4), sub1 the rest
    {
        const int base = e0 + nfull * 8;
        const int r    = e1 - base;
        const int tEnd = (r < sub * 4 + 4) ? r : sub * 4 + 4;
        for (int t = sub * 4; t < tEnd; t++) {
            uint4 t0 = *(const uint4*)(T + (size_t)srcE[base + t] * 64 + c8);
            a0 += b2f_lo(t0.x); a1 += b2f_hi(t0.x);
            a2 += b2f_lo(t0.y); a3 += b2f_hi(t0.y);
            a4 += b2f_lo(t0.z); a5 += b2f_hi(t0.z);
            a6 += b2f_lo(t0.w); a7 += b2f_hi(t0.w);
        }
    }

    // combine the two half-node groups (lanes g and g^8 hold same columns)
    a0 += __shfl_xor(a0, 8); a1 += __shfl_xor(a1, 8);
    a2 += __shfl_xor(a2, 8); a3 += __shfl_xor(a3, 8);
    a4 += __shfl_xor(a4, 8); a5 += __shfl_xor(a5, 8);
    a6 += __shfl_xor(a6, 8); a7 += __shfl_xor(a7, 8);

    if (sub == 0) {
        if constexpr (OUT_F32) {
            float* q = (float*)Hv + (size_t)node * 64 + c8;
            *(float4*)q       = make_float4(a0, a1, a2, a3);
            *(float4*)(q + 4) = make_float4(a4, a5, a6, a7);
        } else {
            ushort4 o0, o1;
            o0.x = f2b(a0); o0.y = f2b(a1); o0.z = f2b(a2); o0.w = f2b(a3);
            o1.x = f2b(a4); o1.y = f2b(a5); o1.z = f2b(a6); o1.w = f2b(a7);
            unsigned short* q = (unsigned short*)Hv + (size_t)node * 64 + c8;
            *(ushort4*)q       = o0;
            *(ushort4*)(q + 4) = o1;
        }
    }
}

extern "C" void kernel_launch(void* const* d_in, const int* in_sizes, int n_in,
                              void* d_out, int out_size, void* d_ws, size_t ws_size,
                              hipStream_t stream) {
    const int*   src  = (const int*)d_in[0];
    const int*   dst  = (const int*)d_in[1];
    const float* feat = (const float*)d_in[2];
    const float* W1   = (const float*)d_in[3];
    const float* W2   = (const float*)d_in[4];
    const float* W3   = (const float*)d_in[5];
    float* out = (float*)d_out;

    // ws layout (bytes): T@0, H@5.25M, rowptr@10.5M, Wt123 after.
    char* wsb = (char*)d_ws;
    unsigned short* T  = (unsigned short*)wsb;
    unsigned short* H  = (unsigned short*)(wsb + (size_t)5505024);
    int* rowptr        = (int*)(wsb + (size_t)11010048);
    unsigned short* Wt123 = (unsigned short*)(wsb + (size_t)11010048 + 163968);

    const int scatterBlocks = (N_NODES + 15) / 16;   // 2500 (4 nodes x 4 waves)

    // out = S^3 . (X @ (W1 W2 W3))  — S = segment-sum, commutes with W (no nonlinearity)
    prep<<<RP_BLOCKS + W_BLOCKS, 256, 0, stream>>>(dst, rowptr, W1, W2, W3, Wt123);
    gemm_mfma64<<<625, 256, 0, stream>>>(feat, Wt123, T);
    scatter8<false><<<scatterBlocks, 256, 0, stream>>>(T, src, rowptr, H);
    scatter8<false><<<scatterBlocks, 256, 0, stream>>>(H, src, rowptr, T);
    scatter8<true><<<scatterBlocks, 256, 0, stream>>>(T, src, rowptr, out);
}

// Round 13
// 134.318 us; speedup vs baseline: 1.0694x; 1.0694x over previous
//
#include <hip/hip_runtime.h>
#include <hip/hip_bf16.h>

#define N_NODES 40000
#define N_EDGES 640000

typedef __attribute__((ext_vector_type(8))) short bfrag;   // 8 bf16
typedef __attribute__((ext_vector_type(4))) float ffrag;   // 4 fp32 acc

__device__ __forceinline__ float b2f_lo(unsigned u) {
    return __builtin_bit_cast(float, u << 16);
}
__device__ __forceinline__ float b2f_hi(unsigned u) {
    return __builtin_bit_cast(float, u & 0xffff0000u);
}
__device__ __forceinline__ unsigned short f2b(float f) {
    return __builtin_bit_cast(unsigned short, __float2bfloat16(f));
}

// ---------------- prep: rowptr (int4 adjacent-diff) + Wt123 (k-parallel) ----
// blocks [0, RP): rowptr. Each thread handles 4 edges via one int4 load.
// blocks [RP, RP+32): weight chain, ONE WAVE PER k (128 waves):
//   u = W1[k,:] @ W2  (lane owns 2 cols, coalesced float2 loads)
//   Wt123[:,k] = u @ W3  (u via LDS broadcast, W3 rows coalesced)
#define RP_BLOCKS 782     // ceil((640000/4 + 40001)/256)
#define W_BLOCKS  32
__global__ __launch_bounds__(256) void prep(const int* __restrict__ dst,
                                            int* __restrict__ rowptr,
                                            const float* __restrict__ W1,
                                            const float* __restrict__ W2,
                                            const float* __restrict__ W3,
                                            unsigned short* __restrict__ Wt123) {
    __shared__ float uS[4][128];
    const int bid = blockIdx.x;
    if (bid < RP_BLOCKS) {
        int i = bid * 256 + threadIdx.x;
        if (i < N_EDGES / 4) {
            int e = i * 4;
            int4 d4 = *(const int4*)(dst + e);
            int dp = (e == 0) ? -1 : dst[e - 1];
            for (int n = dp + 1;   n <= d4.x; n++) rowptr[n] = e;
            for (int n = d4.x + 1; n <= d4.y; n++) rowptr[n] = e + 1;
            for (int n = d4.y + 1; n <= d4.z; n++) rowptr[n] = e + 2;
            for (int n = d4.z + 1; n <= d4.w; n++) rowptr[n] = e + 3;
        } else if (i < N_EDGES / 4 + N_NODES + 1) {
            int n = i - N_EDGES / 4;           // 0..N_NODES
            if (n > dst[N_EDGES - 1]) rowptr[n] = N_EDGES;
        }
        return;
    }

    // weight chain: one wave per k (128 waves) — latency hidden by TLP
    const int wv   = threadIdx.x >> 6;
    const int lane = threadIdx.x & 63;
    const int k    = (bid - RP_BLOCKS) * 4 + wv;   // 0..127

    float u0 = 0.f, u1 = 0.f;
    const float* w1p = W1 + k * 128;
    const float* w2p = W2 + 2 * lane;
#pragma unroll 8
    for (int j = 0; j < 128; j++) {
        float a  = w1p[j];
        float2 w = *(const float2*)(w2p + (size_t)j * 128);
        u0 += a * w.x;
        u1 += a * w.y;
    }
    uS[wv][2 * lane]     = u0;
    uS[wv][2 * lane + 1] = u1;
    __syncthreads();

    float acc = 0.f;
    const float* w3p = W3 + lane;
#pragma unroll 8
    for (int l = 0; l < 128; l++)
        acc += uS[wv][l] * w3p[(size_t)l * 64];
    Wt123[lane * 128 + k] = f2b(acc);
}

// ---------------- MFMA GEMM: T[N,64] = bf16( X[N,128] @ W123 ) ----------------
// Fragments straight from global (16B contiguous/lane); no LDS. 64 rows/block.
__global__ __launch_bounds__(256) void gemm_mfma64(const float* __restrict__ X,
                                                   const unsigned short* __restrict__ Wt,
                                                   unsigned short* __restrict__ Y) {
    const int wv   = threadIdx.x >> 6;
    const int lane = threadIdx.x & 63;
    const int ml   = lane & 15;
    const int quad = lane >> 4;
    const int row0 = blockIdx.x * 64 + wv * 16;

    ffrag acc[4];
#pragma unroll
    for (int c = 0; c < 4; c++) acc[c] = (ffrag)0.f;

#pragma unroll
    for (int kb = 0; kb < 128; kb += 32) {
        const float* p = X + (size_t)(row0 + ml) * 128 + kb + quad * 8;
        float4 u0 = *(const float4*)p;
        float4 u1 = *(const float4*)(p + 4);
        bfrag a;
        a[0] = (short)f2b(u0.x); a[1] = (short)f2b(u0.y);
        a[2] = (short)f2b(u0.z); a[3] = (short)f2b(u0.w);
        a[4] = (short)f2b(u1.x); a[5] = (short)f2b(u1.y);
        a[6] = (short)f2b(u1.z); a[7] = (short)f2b(u1.w);
#pragma unroll
        for (int c = 0; c < 4; c++) {
            const int col = c * 16 + ml;
            bfrag b = *(const bfrag*)(Wt + (size_t)col * 128 + kb + quad * 8);
            acc[c] = __builtin_amdgcn_mfma_f32_16x16x32_bf16(a, b, acc[c], 0, 0, 0);
        }
    }
#pragma unroll
    for (int c = 0; c < 4; c++)
#pragma unroll
        for (int i = 0; i < 4; i++)
            Y[(size_t)(row0 + quad * 4 + i) * 64 + c * 16 + ml] = f2b(acc[c][i]);
}

// ---------------- CSR scatter, D=64, bf16 in (R11 proven config) ----------------
// 8 nodes per wave (one per 8-lane group); lane owns 8 cols via one 16B uint4
// load (128B/row); unroll-4 (4 gathers in flight); contiguous stores.
// R12 lesson: splitting nodes across two groups (+shfl combine) regressed
// +2.8 us/scatter — 4 in-flight loads already cover L2 latency at 5000 waves.
template<bool OUT_F32>
__global__ __launch_bounds__(256) void scatter8(const unsigned short* __restrict__ T,
                                                const int* __restrict__ srcE,
                                                const int* __restrict__ rowptr,
                                                void* __restrict__ Hv) {
    const int wave = blockIdx.x * 4 + (threadIdx.x >> 6);
    const int lane = threadIdx.x & 63;
    const int g    = lane >> 3;          // group 0..7 -> node
    const int c8   = (lane & 7) * 8;     // cols c8..c8+7
    const int node = wave * 8 + g;
    if (node >= N_NODES) return;
    const int e0 = rowptr[node], e1 = rowptr[node + 1];

    float a0 = 0.f, a1 = 0.f, a2 = 0.f, a3 = 0.f;
    float a4 = 0.f, a5 = 0.f, a6 = 0.f, a7 = 0.f;
    int e = e0;
    for (; e + 4 <= e1; e += 4) {
        int s0 = srcE[e], s1 = srcE[e + 1], s2 = srcE[e + 2], s3 = srcE[e + 3];
        uint4 t0 = *(const uint4*)(T + (size_t)s0 * 64 + c8);
        uint4 t1 = *(const uint4*)(T + (size_t)s1 * 64 + c8);
        uint4 t2 = *(const uint4*)(T + (size_t)s2 * 64 + c8);
        uint4 t3 = *(const uint4*)(T + (size_t)s3 * 64 + c8);
        a0 += (b2f_lo(t0.x) + b2f_lo(t1.x)) + (b2f_lo(t2.x) + b2f_lo(t3.x));
        a1 += (b2f_hi(t0.x) + b2f_hi(t1.x)) + (b2f_hi(t2.x) + b2f_hi(t3.x));
        a2 += (b2f_lo(t0.y) + b2f_lo(t1.y)) + (b2f_lo(t2.y) + b2f_lo(t3.y));
        a3 += (b2f_hi(t0.y) + b2f_hi(t1.y)) + (b2f_hi(t2.y) + b2f_hi(t3.y));
        a4 += (b2f_lo(t0.z) + b2f_lo(t1.z)) + (b2f_lo(t2.z) + b2f_lo(t3.z));
        a5 += (b2f_hi(t0.z) + b2f_hi(t1.z)) + (b2f_hi(t2.z) + b2f_hi(t3.z));
        a6 += (b2f_lo(t0.w) + b2f_lo(t1.w)) + (b2f_lo(t2.w) + b2f_lo(t3.w));
        a7 += (b2f_hi(t0.w) + b2f_hi(t1.w)) + (b2f_hi(t2.w) + b2f_hi(t3.w));
    }
    for (; e < e1; e++) {
        uint4 t0 = *(const uint4*)(T + (size_t)srcE[e] * 64 + c8);
        a0 += b2f_lo(t0.x); a1 += b2f_hi(t0.x);
        a2 += b2f_lo(t0.y); a3 += b2f_hi(t0.y);
        a4 += b2f_lo(t0.z); a5 += b2f_hi(t0.z);
        a6 += b2f_lo(t0.w); a7 += b2f_hi(t0.w);
    }

    if constexpr (OUT_F32) {
        float* q = (float*)Hv + (size_t)node * 64 + c8;
        *(float4*)q       = make_float4(a0, a1, a2, a3);
        *(float4*)(q + 4) = make_float4(a4, a5, a6, a7);
    } else {
        ushort4 o0, o1;
        o0.x = f2b(a0); o0.y = f2b(a1); o0.z = f2b(a2); o0.w = f2b(a3);
        o1.x = f2b(a4); o1.y = f2b(a5); o1.z = f2b(a6); o1.w = f2b(a7);
        unsigned short* q = (unsigned short*)Hv + (size_t)node * 64 + c8;
        *(ushort4*)q       = o0;
        *(ushort4*)(q + 4) = o1;
    }
}

extern "C" void kernel_launch(void* const* d_in, const int* in_sizes, int n_in,
                              void* d_out, int out_size, void* d_ws, size_t ws_size,
                              hipStream_t stream) {
    const int*   src  = (const int*)d_in[0];
    const int*   dst  = (const int*)d_in[1];
    const float* feat = (const float*)d_in[2];
    const float* W1   = (const float*)d_in[3];
    const float* W2   = (const float*)d_in[4];
    const float* W3   = (const float*)d_in[5];
    float* out = (float*)d_out;

    // ws layout (bytes): T@0, H@5.25M, rowptr@10.5M, Wt123 after.
    char* wsb = (char*)d_ws;
    unsigned short* T  = (unsigned short*)wsb;
    unsigned short* H  = (unsigned short*)(wsb + (size_t)5505024);
    int* rowptr        = (int*)(wsb + (size_t)11010048);
    unsigned short* Wt123 = (unsigned short*)(wsb + (size_t)11010048 + 163968);

    const int scatterBlocks = (N_NODES + 31) / 32;   // 1250 (8 nodes x 4 waves)

    // out = S^3 . (X @ (W1 W2 W3))  — S = segment-sum, commutes with W (no nonlinearity)
    prep<<<RP_BLOCKS + W_BLOCKS, 256, 0, stream>>>(dst, rowptr, W1, W2, W3, Wt123);
    gemm_mfma64<<<625, 256, 0, stream>>>(feat, Wt123, T);
    scatter8<false><<<scatterBlocks, 256, 0, stream>>>(T, src, rowptr, H);
    scatter8<false><<<scatterBlocks, 256, 0, stream>>>(H, src, rowptr, T);
    scatter8<true><<<scatterBlocks, 256, 0, stream>>>(T, src, rowptr, out);
}